// Round 1
// baseline (665.713 us; speedup 1.0000x reference)
//
#include <hip/hip_runtime.h>
#include <math.h>

// ---------------------------------------------------------------------------
// GGNN layer: X = relu(Agg(nf@Wm)+bm); Z=sig(Agg([X,H]@Wz)+bz);
// R=sig(Agg([X,H]@Wr)+br); Ht=tanh(Agg([X,R*H]@Wh)+bh); out=Z*H+(1-Z)*Ht
// Agg(T)[v] = sum over in-edges (src->v) of T[src].  CSR-by-dst built per call.
// ---------------------------------------------------------------------------

__device__ __forceinline__ float sigmoidf(float x) {
  return 1.0f / (1.0f + __expf(-x));
}

__global__ void zero_ints(int* __restrict__ p, int n) {
  int i = blockIdx.x * blockDim.x + threadIdx.x;
  if (i < n) p[i] = 0;
}

__global__ void count_kernel(const int* __restrict__ dst, int* __restrict__ cnt, int E) {
  int e = blockIdx.x * blockDim.x + threadIdx.x;
  if (e < E) atomicAdd(&cnt[dst[e]], 1);
}

// single-workgroup exclusive scan over n counts -> off[0..n], cur[0..n]
__global__ void scan_kernel(const int* __restrict__ cnt, int* __restrict__ off,
                            int* __restrict__ cur, int n) {
  __shared__ int wsum[16];
  __shared__ int carry_s;
  const int tid = threadIdx.x;            // 1024 threads
  const int lane = tid & 63, wid = tid >> 6;
  if (tid == 0) carry_s = 0;
  __syncthreads();
  for (int base = 0; base < n; base += 1024) {
    int i = base + tid;
    int v = (i < n) ? cnt[i] : 0;
    int x = v;
    #pragma unroll
    for (int d = 1; d < 64; d <<= 1) {
      int y = __shfl_up(x, d);
      if (lane >= d) x += y;
    }
    if (lane == 63) wsum[wid] = x;
    __syncthreads();
    if (wid == 0) {
      int ws = (lane < 16) ? wsum[lane] : 0;
      #pragma unroll
      for (int d = 1; d < 16; d <<= 1) {
        int y = __shfl_up(ws, d);
        if (lane >= d) ws += y;
      }
      if (lane < 16) wsum[lane] = ws;
    }
    __syncthreads();
    int carry = carry_s;
    int woff = (wid > 0) ? wsum[wid - 1] : 0;
    int incl = x + woff;            // inclusive within chunk
    int excl = carry + incl - v;    // exclusive global
    if (i < n) { off[i] = excl; cur[i] = excl; }
    __syncthreads();                // all reads of carry_s / wsum done
    if (tid == 1023) carry_s = carry + incl;
    __syncthreads();
  }
  if (threadIdx.x == 0) { off[n] = carry_s; cur[n] = carry_s; }
}

__global__ void fill_kernel(const int* __restrict__ src, const int* __restrict__ dst,
                            int* __restrict__ cur, int* __restrict__ esrc, int E) {
  int e = blockIdx.x * blockDim.x + threadIdx.x;
  if (e < E) {
    int d = dst[e];
    int p = atomicAdd(&cur[d], 1);
    esrc[p] = src[e];
  }
}

// ---------------------------------------------------------------------------
// C[N,128] = A0@W0 (+ A1@W1).  Each K = 128.  Block: 256 thr, 64 rows x 128 cols.
// Thread: 8 rows x 4 cols. W tile + A tile staged in LDS, k-chunk = 64.
// ---------------------------------------------------------------------------
template <int TERMS>
__global__ __launch_bounds__(256) void gemm128(
    const float* __restrict__ A0, const float* __restrict__ W0,
    const float* __restrict__ A1, const float* __restrict__ W1,
    float* __restrict__ C, int N) {
  __shared__ float As[64][68];     // padded: row stride 68 (bank shift 4, f4-aligned)
  __shared__ float Ws[64][128];
  const int tid = threadIdx.x;
  const int cg = tid & 31;         // cols 4*cg .. 4*cg+3
  const int rg = tid >> 5;         // rows rg*8 .. rg*8+7
  const int block_row = blockIdx.x * 64;

  float acc[8][4];
  #pragma unroll
  for (int i = 0; i < 8; ++i)
    acc[i][0] = acc[i][1] = acc[i][2] = acc[i][3] = 0.0f;

  #pragma unroll
  for (int term = 0; term < TERMS; ++term) {
    const float* __restrict__ A = term ? A1 : A0;
    const float* __restrict__ W = term ? W1 : W0;
    for (int kk = 0; kk < 128; kk += 64) {
      __syncthreads();   // protect LDS from previous chunk's readers
      {  // stage A: 64 rows x 64 k
        const int tr = tid >> 4;
        const int tc = (tid & 15) * 4;
        #pragma unroll
        for (int p = 0; p < 4; ++p) {
          int r = tr + p * 16;
          int row = block_row + r;
          float4 v = make_float4(0.f, 0.f, 0.f, 0.f);
          if (row < N) v = *(const float4*)&A[(size_t)row * 128 + kk + tc];
          *(float4*)&As[r][tc] = v;
        }
      }
      {  // stage W: 64 k x 128 cols
        const int wr = tid >> 5;
        const int wc = (tid & 31) * 4;
        #pragma unroll
        for (int p = 0; p < 8; ++p) {
          int k = wr + p * 8;
          *(float4*)&Ws[k][wc] = *(const float4*)&W[(size_t)(kk + k) * 128 + wc];
        }
      }
      __syncthreads();
      #pragma unroll 16
      for (int k = 0; k < 64; ++k) {
        float4 w = *(const float4*)&Ws[k][cg * 4];
        float a[8];
        #pragma unroll
        for (int i = 0; i < 8; ++i) a[i] = As[rg * 8 + i][k];
        #pragma unroll
        for (int i = 0; i < 8; ++i) {
          acc[i][0] = fmaf(a[i], w.x, acc[i][0]);
          acc[i][1] = fmaf(a[i], w.y, acc[i][1]);
          acc[i][2] = fmaf(a[i], w.z, acc[i][2]);
          acc[i][3] = fmaf(a[i], w.w, acc[i][3]);
        }
      }
    }
  }
  #pragma unroll
  for (int i = 0; i < 8; ++i) {
    int row = block_row + rg * 8 + i;
    if (row < N) {
      float4 v = make_float4(acc[i][0], acc[i][1], acc[i][2], acc[i][3]);
      *(float4*)&C[(size_t)row * 128 + cg * 4] = v;
    }
  }
}

// ---------------------------------------------------------------------------
// Gathers: one wave (64 lanes) per node, lane covers 2 cols (float2 = 512B/row).
// ---------------------------------------------------------------------------
__global__ void gather_relu(const float* __restrict__ T, const int* __restrict__ off,
                            const int* __restrict__ esrc, const float* __restrict__ bias,
                            float* __restrict__ X, int N) {
  int w = (blockIdx.x * blockDim.x + threadIdx.x) >> 6;
  int lane = threadIdx.x & 63;
  if (w >= N) return;
  int beg = off[w], end = off[w + 1];
  float ax = 0.f, ay = 0.f;
  for (int j = beg; j < end; ++j) {
    int r = esrc[j];
    float2 v = *(const float2*)&T[(size_t)r * 128 + lane * 2];
    ax += v.x; ay += v.y;
  }
  float2 b = *(const float2*)&bias[lane * 2];
  float2 o;
  o.x = fmaxf(ax + b.x, 0.f);
  o.y = fmaxf(ay + b.y, 0.f);
  *(float2*)&X[(size_t)w * 128 + lane * 2] = o;
}

__global__ void gather_zr(const float* __restrict__ Tz, const float* __restrict__ Tr,
                          const int* __restrict__ off, const int* __restrict__ esrc,
                          const float* __restrict__ bz, const float* __restrict__ br,
                          const float* __restrict__ H,
                          float* __restrict__ Z, float* __restrict__ G, int N) {
  int w = (blockIdx.x * blockDim.x + threadIdx.x) >> 6;
  int lane = threadIdx.x & 63;
  if (w >= N) return;
  int beg = off[w], end = off[w + 1];
  float zx = 0.f, zy = 0.f, rx = 0.f, ry = 0.f;
  for (int j = beg; j < end; ++j) {
    int r = esrc[j];
    size_t p = (size_t)r * 128 + lane * 2;
    float2 vz = *(const float2*)&Tz[p];
    float2 vr = *(const float2*)&Tr[p];
    zx += vz.x; zy += vz.y;
    rx += vr.x; ry += vr.y;
  }
  float2 bzv = *(const float2*)&bz[lane * 2];
  float2 brv = *(const float2*)&br[lane * 2];
  float z0 = sigmoidf(zx + bzv.x), z1 = sigmoidf(zy + bzv.y);
  float r0 = sigmoidf(rx + brv.x), r1 = sigmoidf(ry + brv.y);
  size_t q = (size_t)w * 128 + lane * 2;
  float2 h = *(const float2*)&H[q];
  float2 zo = {z0, z1};
  float2 go = {r0 * h.x, r1 * h.y};
  *(float2*)&Z[q] = zo;
  *(float2*)&G[q] = go;
}

__global__ void gather_out(const float* __restrict__ Th, const int* __restrict__ off,
                           const int* __restrict__ esrc, const float* __restrict__ bh,
                           const float* __restrict__ Z, const float* __restrict__ H,
                           float* __restrict__ out, int N) {
  int w = (blockIdx.x * blockDim.x + threadIdx.x) >> 6;
  int lane = threadIdx.x & 63;
  if (w >= N) return;
  int beg = off[w], end = off[w + 1];
  float ax = 0.f, ay = 0.f;
  for (int j = beg; j < end; ++j) {
    int r = esrc[j];
    float2 v = *(const float2*)&Th[(size_t)r * 128 + lane * 2];
    ax += v.x; ay += v.y;
  }
  float2 b = *(const float2*)&bh[lane * 2];
  float h0 = tanhf(ax + b.x), h1 = tanhf(ay + b.y);
  size_t q = (size_t)w * 128 + lane * 2;
  float2 z = *(const float2*)&Z[q];
  float2 h = *(const float2*)&H[q];
  float2 o;
  o.x = z.x * h.x + (1.0f - z.x) * h0;
  o.y = z.y * h.y + (1.0f - z.y) * h1;
  *(float2*)&out[q] = o;
}

// ---------------------------------------------------------------------------

extern "C" void kernel_launch(void* const* d_in, const int* in_sizes, int n_in,
                              void* d_out, int out_size, void* d_ws, size_t ws_size,
                              hipStream_t stream) {
  const float* nf = (const float*)d_in[0];
  const float* H  = (const float*)d_in[1];
  const int*   ei = (const int*)d_in[2];
  const float* Wm = (const float*)d_in[3];
  const float* bm = (const float*)d_in[4];
  const float* Wz = (const float*)d_in[5];
  const float* bz = (const float*)d_in[6];
  const float* Wr = (const float*)d_in[7];
  const float* br = (const float*)d_in[8];
  const float* Wh = (const float*)d_in[9];
  const float* bh = (const float*)d_in[10];
  float* out = (float*)d_out;

  const int N = in_sizes[0] / 128;
  const int E = in_sizes[2] / 2;
  const int* src = ei;       // edge_index[0]
  const int* dst = ei + E;   // edge_index[1]

  // workspace layout (512B aligned slices)
  char* ws = (char*)d_ws;
  size_t o = 0;
  auto alloc = [&](size_t bytes) {
    char* p = ws + o;
    o = (o + bytes + 511) & ~(size_t)511;
    return p;
  };
  int* cnt   = (int*)alloc((size_t)N * 4);
  int* off   = (int*)alloc((size_t)(N + 1) * 4);
  int* cur   = (int*)alloc((size_t)(N + 1) * 4);
  int* esrc  = (int*)alloc((size_t)E * 4);
  float* T0  = (float*)alloc((size_t)N * 128 * 4);
  float* X   = (float*)alloc((size_t)N * 128 * 4);
  float* Z   = (float*)alloc((size_t)N * 128 * 4);
  float* G   = (float*)alloc((size_t)N * 128 * 4);
  float* T1  = out;  // d_out doubles as T_r scratch (dead before final write)

  // --- build CSR by dst ---
  zero_ints<<<(N + 255) / 256, 256, 0, stream>>>(cnt, N);
  count_kernel<<<(E + 255) / 256, 256, 0, stream>>>(dst, cnt, E);
  scan_kernel<<<1, 1024, 0, stream>>>(cnt, off, cur, N);
  fill_kernel<<<(E + 255) / 256, 256, 0, stream>>>(src, dst, cur, esrc, E);

  const int gblk = (N * 64 + 255) / 256;   // one wave per node
  const int mblk = (N + 63) / 64;

  // --- main conv: X = relu(Agg(nf@Wm) + bm) ---
  gemm128<1><<<mblk, 256, 0, stream>>>(nf, Wm, nullptr, nullptr, T0, N);
  gather_relu<<<gblk, 256, 0, stream>>>(T0, off, esrc, bm, X, N);

  // --- Z and R convs (share edge traversal) ---
  gemm128<2><<<mblk, 256, 0, stream>>>(X, Wz, H, Wz + 128 * 128, T0, N);
  gemm128<2><<<mblk, 256, 0, stream>>>(X, Wr, H, Wr + 128 * 128, T1, N);
  gather_zr<<<gblk, 256, 0, stream>>>(T0, T1, off, esrc, bz, br, H, Z, G, N);

  // --- H_tilde conv + output ---
  gemm128<2><<<mblk, 256, 0, stream>>>(X, Wh, G, Wh + 128 * 128, T0, N);
  gather_out<<<gblk, 256, 0, stream>>>(T0, off, esrc, bh, Z, H, out, N);
}

// Round 2
// 508.487 us; speedup vs baseline: 1.3092x; 1.3092x over previous
//
#include <hip/hip_runtime.h>
#include <hip/hip_fp16.h>
#include <math.h>

// ---------------------------------------------------------------------------
// GGNN layer: X = relu(Agg(nf@Wm)+bm); Z=sig(Agg([X,H]@Wz)+bz);
// R=sig(Agg([X,H]@Wr)+br); Ht=tanh(Agg([X,R*H]@Wh)+bh); out=Z*H+(1-Z)*Ht
// Agg(T)[v] = sum over in-edges (src->v) of T[src].  CSR-by-dst built per call.
// Gathered tensors stored f16 (halves gather bytes); Tz/Tr packed interleaved
// [N,256] so gather_zr reads ONE 512B row per edge. GEMMs compute in f32.
// ---------------------------------------------------------------------------

__device__ __forceinline__ float sigmoidf(float x) {
  return 1.0f / (1.0f + __expf(-x));
}

__device__ __forceinline__ float2 h2f2(unsigned int u) {
  __half2 h = *reinterpret_cast<__half2*>(&u);
  return __half22float2(h);
}

__global__ void zero_ints(int* __restrict__ p, int n) {
  int i = blockIdx.x * blockDim.x + threadIdx.x;
  if (i < n) p[i] = 0;
}

__global__ void count_kernel(const int* __restrict__ dst, int* __restrict__ cnt, int E) {
  int e = blockIdx.x * blockDim.x + threadIdx.x;
  if (e < E) atomicAdd(&cnt[dst[e]], 1);
}

// single-workgroup exclusive scan over n counts -> off[0..n], cur[0..n]
__global__ void scan_kernel(const int* __restrict__ cnt, int* __restrict__ off,
                            int* __restrict__ cur, int n) {
  __shared__ int wsum[16];
  __shared__ int carry_s;
  const int tid = threadIdx.x;            // 1024 threads
  const int lane = tid & 63, wid = tid >> 6;
  if (tid == 0) carry_s = 0;
  __syncthreads();
  for (int base = 0; base < n; base += 1024) {
    int i = base + tid;
    int v = (i < n) ? cnt[i] : 0;
    int x = v;
    #pragma unroll
    for (int d = 1; d < 64; d <<= 1) {
      int y = __shfl_up(x, d);
      if (lane >= d) x += y;
    }
    if (lane == 63) wsum[wid] = x;
    __syncthreads();
    if (wid == 0) {
      int ws = (lane < 16) ? wsum[lane] : 0;
      #pragma unroll
      for (int d = 1; d < 16; d <<= 1) {
        int y = __shfl_up(ws, d);
        if (lane >= d) ws += y;
      }
      if (lane < 16) wsum[lane] = ws;
    }
    __syncthreads();
    int carry = carry_s;
    int woff = (wid > 0) ? wsum[wid - 1] : 0;
    int incl = x + woff;            // inclusive within chunk
    int excl = carry + incl - v;    // exclusive global
    if (i < n) { off[i] = excl; cur[i] = excl; }
    __syncthreads();                // all reads of carry_s / wsum done
    if (tid == 1023) carry_s = carry + incl;
    __syncthreads();
  }
  if (threadIdx.x == 0) { off[n] = carry_s; cur[n] = carry_s; }
}

__global__ void fill_kernel(const int* __restrict__ src, const int* __restrict__ dst,
                            int* __restrict__ cur, int* __restrict__ esrc, int E) {
  int e = blockIdx.x * blockDim.x + threadIdx.x;
  if (e < E) {
    int d = dst[e];
    int p = atomicAdd(&cur[d], 1);
    esrc[p] = src[e];
  }
}

// ---------------------------------------------------------------------------
// C_f16[row*ldc + col_off + c] = (A0@W0 (+ A1@W1))[row][c].  K = 128 per term.
// Block: 256 thr, 64 rows x 128 cols. Thread: 8 rows x 4 cols. f32 compute.
// ---------------------------------------------------------------------------
template <int TERMS>
__global__ __launch_bounds__(256) void gemm128_f16(
    const float* __restrict__ A0, const float* __restrict__ W0,
    const float* __restrict__ A1, const float* __restrict__ W1,
    __half* __restrict__ C, int ldc, int col_off, int N) {
  __shared__ float As[64][68];     // padded: row stride 68
  __shared__ float Ws[64][128];
  const int tid = threadIdx.x;
  const int cg = tid & 31;         // cols 4*cg .. 4*cg+3
  const int rg = tid >> 5;         // rows rg*8 .. rg*8+7
  const int block_row = blockIdx.x * 64;

  float acc[8][4];
  #pragma unroll
  for (int i = 0; i < 8; ++i)
    acc[i][0] = acc[i][1] = acc[i][2] = acc[i][3] = 0.0f;

  #pragma unroll
  for (int term = 0; term < TERMS; ++term) {
    const float* __restrict__ A = term ? A1 : A0;
    const float* __restrict__ W = term ? W1 : W0;
    for (int kk = 0; kk < 128; kk += 64) {
      __syncthreads();   // protect LDS from previous chunk's readers
      {  // stage A: 64 rows x 64 k
        const int tr = tid >> 4;
        const int tc = (tid & 15) * 4;
        #pragma unroll
        for (int p = 0; p < 4; ++p) {
          int r = tr + p * 16;
          int row = block_row + r;
          float4 v = make_float4(0.f, 0.f, 0.f, 0.f);
          if (row < N) v = *(const float4*)&A[(size_t)row * 128 + kk + tc];
          *(float4*)&As[r][tc] = v;
        }
      }
      {  // stage W: 64 k x 128 cols
        const int wr = tid >> 5;
        const int wc = (tid & 31) * 4;
        #pragma unroll
        for (int p = 0; p < 8; ++p) {
          int k = wr + p * 8;
          *(float4*)&Ws[k][wc] = *(const float4*)&W[(size_t)(kk + k) * 128 + wc];
        }
      }
      __syncthreads();
      #pragma unroll 16
      for (int k = 0; k < 64; ++k) {
        float4 w = *(const float4*)&Ws[k][cg * 4];
        float a[8];
        #pragma unroll
        for (int i = 0; i < 8; ++i) a[i] = As[rg * 8 + i][k];
        #pragma unroll
        for (int i = 0; i < 8; ++i) {
          acc[i][0] = fmaf(a[i], w.x, acc[i][0]);
          acc[i][1] = fmaf(a[i], w.y, acc[i][1]);
          acc[i][2] = fmaf(a[i], w.z, acc[i][2]);
          acc[i][3] = fmaf(a[i], w.w, acc[i][3]);
        }
      }
    }
  }
  #pragma unroll
  for (int i = 0; i < 8; ++i) {
    int row = block_row + rg * 8 + i;
    if (row < N) {
      __half2 p0 = __floats2half2_rn(acc[i][0], acc[i][1]);
      __half2 p1 = __floats2half2_rn(acc[i][2], acc[i][3]);
      uint2 u;
      u.x = *(unsigned int*)&p0;
      u.y = *(unsigned int*)&p1;
      *(uint2*)&C[(size_t)row * ldc + col_off + cg * 4] = u;
    }
  }
}

// ---------------------------------------------------------------------------
// Gathers: one wave per node. f16 rows; 4x edge unroll for memory-level par.
// ---------------------------------------------------------------------------
__global__ void gather_relu(const __half* __restrict__ T, const int* __restrict__ off,
                            const int* __restrict__ esrc, const float* __restrict__ bias,
                            float* __restrict__ X, int N) {
  int w = (blockIdx.x * blockDim.x + threadIdx.x) >> 6;
  int lane = threadIdx.x & 63;
  if (w >= N) return;
  int beg = off[w], end = off[w + 1];
  float ax = 0.f, ay = 0.f;
  int j = beg;
  for (; j + 4 <= end; j += 4) {
    int r0 = esrc[j], r1 = esrc[j + 1], r2 = esrc[j + 2], r3 = esrc[j + 3];
    unsigned int v0 = *(const unsigned int*)&T[(size_t)r0 * 128 + lane * 2];
    unsigned int v1 = *(const unsigned int*)&T[(size_t)r1 * 128 + lane * 2];
    unsigned int v2 = *(const unsigned int*)&T[(size_t)r2 * 128 + lane * 2];
    unsigned int v3 = *(const unsigned int*)&T[(size_t)r3 * 128 + lane * 2];
    float2 f0 = h2f2(v0), f1 = h2f2(v1), f2 = h2f2(v2), f3 = h2f2(v3);
    ax += (f0.x + f1.x) + (f2.x + f3.x);
    ay += (f0.y + f1.y) + (f2.y + f3.y);
  }
  for (; j < end; ++j) {
    unsigned int v = *(const unsigned int*)&T[(size_t)esrc[j] * 128 + lane * 2];
    float2 f = h2f2(v);
    ax += f.x; ay += f.y;
  }
  float2 b = *(const float2*)&bias[lane * 2];
  float2 o;
  o.x = fmaxf(ax + b.x, 0.f);
  o.y = fmaxf(ay + b.y, 0.f);
  *(float2*)&X[(size_t)w * 128 + lane * 2] = o;
}

// packed T: [N][256] f16 rows = [z0..z127, r0..r127]. Lane covers 4 cols (8B).
// Lanes 0-31: z cols 4l..4l+3 -> Z.  Lanes 32-63: r cols -> G = sig(r)*H.
__global__ void gather_zr(const __half* __restrict__ P, const int* __restrict__ off,
                          const int* __restrict__ esrc, const float* __restrict__ bz,
                          const float* __restrict__ br, const float* __restrict__ H,
                          float* __restrict__ Z, float* __restrict__ G, int N) {
  int w = (blockIdx.x * blockDim.x + threadIdx.x) >> 6;
  int lane = threadIdx.x & 63;
  if (w >= N) return;
  int beg = off[w], end = off[w + 1];
  float a0 = 0.f, a1 = 0.f, a2 = 0.f, a3 = 0.f;
  int j = beg;
  for (; j + 4 <= end; j += 4) {
    int r0 = esrc[j], r1 = esrc[j + 1], r2 = esrc[j + 2], r3 = esrc[j + 3];
    uint2 v0 = *(const uint2*)&P[(size_t)r0 * 256 + lane * 4];
    uint2 v1 = *(const uint2*)&P[(size_t)r1 * 256 + lane * 4];
    uint2 v2 = *(const uint2*)&P[(size_t)r2 * 256 + lane * 4];
    uint2 v3 = *(const uint2*)&P[(size_t)r3 * 256 + lane * 4];
    float2 f0a = h2f2(v0.x), f0b = h2f2(v0.y);
    float2 f1a = h2f2(v1.x), f1b = h2f2(v1.y);
    float2 f2a = h2f2(v2.x), f2b = h2f2(v2.y);
    float2 f3a = h2f2(v3.x), f3b = h2f2(v3.y);
    a0 += (f0a.x + f1a.x) + (f2a.x + f3a.x);
    a1 += (f0a.y + f1a.y) + (f2a.y + f3a.y);
    a2 += (f0b.x + f1b.x) + (f2b.x + f3b.x);
    a3 += (f0b.y + f1b.y) + (f2b.y + f3b.y);
  }
  for (; j < end; ++j) {
    uint2 v = *(const uint2*)&P[(size_t)esrc[j] * 256 + lane * 4];
    float2 fa = h2f2(v.x), fb = h2f2(v.y);
    a0 += fa.x; a1 += fa.y; a2 += fb.x; a3 += fb.y;
  }
  if (lane < 32) {
    int c = lane * 4;
    float4 b = *(const float4*)&bz[c];
    float4 o;
    o.x = sigmoidf(a0 + b.x);
    o.y = sigmoidf(a1 + b.y);
    o.z = sigmoidf(a2 + b.z);
    o.w = sigmoidf(a3 + b.w);
    *(float4*)&Z[(size_t)w * 128 + c] = o;
  } else {
    int c = (lane - 32) * 4;
    float4 b = *(const float4*)&br[c];
    float4 h = *(const float4*)&H[(size_t)w * 128 + c];
    float4 o;
    o.x = sigmoidf(a0 + b.x) * h.x;
    o.y = sigmoidf(a1 + b.y) * h.y;
    o.z = sigmoidf(a2 + b.z) * h.z;
    o.w = sigmoidf(a3 + b.w) * h.w;
    *(float4*)&G[(size_t)w * 128 + c] = o;
  }
}

__global__ void gather_out(const __half* __restrict__ T, const int* __restrict__ off,
                           const int* __restrict__ esrc, const float* __restrict__ bh,
                           const float* __restrict__ Z, const float* __restrict__ H,
                           float* __restrict__ out, int N) {
  int w = (blockIdx.x * blockDim.x + threadIdx.x) >> 6;
  int lane = threadIdx.x & 63;
  if (w >= N) return;
  int beg = off[w], end = off[w + 1];
  float ax = 0.f, ay = 0.f;
  int j = beg;
  for (; j + 4 <= end; j += 4) {
    int r0 = esrc[j], r1 = esrc[j + 1], r2 = esrc[j + 2], r3 = esrc[j + 3];
    unsigned int v0 = *(const unsigned int*)&T[(size_t)r0 * 128 + lane * 2];
    unsigned int v1 = *(const unsigned int*)&T[(size_t)r1 * 128 + lane * 2];
    unsigned int v2 = *(const unsigned int*)&T[(size_t)r2 * 128 + lane * 2];
    unsigned int v3 = *(const unsigned int*)&T[(size_t)r3 * 128 + lane * 2];
    float2 f0 = h2f2(v0), f1 = h2f2(v1), f2 = h2f2(v2), f3 = h2f2(v3);
    ax += (f0.x + f1.x) + (f2.x + f3.x);
    ay += (f0.y + f1.y) + (f2.y + f3.y);
  }
  for (; j < end; ++j) {
    unsigned int v = *(const unsigned int*)&T[(size_t)esrc[j] * 128 + lane * 2];
    float2 f = h2f2(v);
    ax += f.x; ay += f.y;
  }
  float2 b = *(const float2*)&bh[lane * 2];
  float h0 = tanhf(ax + b.x), h1 = tanhf(ay + b.y);
  size_t q = (size_t)w * 128 + lane * 2;
  float2 z = *(const float2*)&Z[q];
  float2 h = *(const float2*)&H[q];
  float2 o;
  o.x = z.x * h.x + (1.0f - z.x) * h0;
  o.y = z.y * h.y + (1.0f - z.y) * h1;
  *(float2*)&out[q] = o;
}

// ---------------------------------------------------------------------------

extern "C" void kernel_launch(void* const* d_in, const int* in_sizes, int n_in,
                              void* d_out, int out_size, void* d_ws, size_t ws_size,
                              hipStream_t stream) {
  const float* nf = (const float*)d_in[0];
  const float* H  = (const float*)d_in[1];
  const int*   ei = (const int*)d_in[2];
  const float* Wm = (const float*)d_in[3];
  const float* bm = (const float*)d_in[4];
  const float* Wz = (const float*)d_in[5];
  const float* bz = (const float*)d_in[6];
  const float* Wr = (const float*)d_in[7];
  const float* br = (const float*)d_in[8];
  const float* Wh = (const float*)d_in[9];
  const float* bh = (const float*)d_in[10];
  float* out = (float*)d_out;

  const int N = in_sizes[0] / 128;
  const int E = in_sizes[2] / 2;
  const int* src = ei;       // edge_index[0]
  const int* dst = ei + E;   // edge_index[1]

  // workspace layout (512B aligned slices)
  char* ws = (char*)d_ws;
  size_t o = 0;
  auto alloc = [&](size_t bytes) {
    char* p = ws + o;
    o = (o + bytes + 511) & ~(size_t)511;
    return p;
  };
  int* cnt      = (int*)alloc((size_t)N * 4);
  int* off      = (int*)alloc((size_t)(N + 1) * 4);
  int* cur      = (int*)alloc((size_t)(N + 1) * 4);
  int* esrc     = (int*)alloc((size_t)E * 4);
  __half* Tm    = (__half*)alloc((size_t)N * 128 * 2);
  __half* Pzr   = (__half*)alloc((size_t)N * 256 * 2);
  __half* Th    = (__half*)alloc((size_t)N * 128 * 2);
  float* X      = (float*)alloc((size_t)N * 128 * 4);
  float* G      = (float*)alloc((size_t)N * 128 * 4);
  float* Z      = out;  // d_out doubles as Z storage (read then overwritten in gather_out)

  // --- build CSR by dst ---
  zero_ints<<<(N + 255) / 256, 256, 0, stream>>>(cnt, N);
  count_kernel<<<(E + 255) / 256, 256, 0, stream>>>(dst, cnt, E);
  scan_kernel<<<1, 1024, 0, stream>>>(cnt, off, cur, N);
  fill_kernel<<<(E + 255) / 256, 256, 0, stream>>>(src, dst, cur, esrc, E);

  const int gblk = (N * 64 + 255) / 256;   // one wave per node
  const int mblk = (N + 63) / 64;

  // --- main conv: X = relu(Agg(nf@Wm) + bm) ---
  gemm128_f16<1><<<mblk, 256, 0, stream>>>(nf, Wm, nullptr, nullptr, Tm, 128, 0, N);
  gather_relu<<<gblk, 256, 0, stream>>>(Tm, off, esrc, bm, X, N);

  // --- Z and R convs (share edge traversal; packed interleaved rows) ---
  gemm128_f16<2><<<mblk, 256, 0, stream>>>(X, Wz, H, Wz + 128 * 128, Pzr, 256, 0, N);
  gemm128_f16<2><<<mblk, 256, 0, stream>>>(X, Wr, H, Wr + 128 * 128, Pzr, 256, 128, N);
  gather_zr<<<gblk, 256, 0, stream>>>(Pzr, off, esrc, bz, br, H, Z, G, N);

  // --- H_tilde conv + output ---
  gemm128_f16<2><<<mblk, 256, 0, stream>>>(X, Wh, G, Wh + 128 * 128, Th, 128, 0, N);
  gather_out<<<gblk, 256, 0, stream>>>(Th, off, esrc, bh, Z, H, out, N);
}

// Round 3
// 334.387 us; speedup vs baseline: 1.9908x; 1.5207x over previous
//
#include <hip/hip_runtime.h>
#include <hip/hip_fp16.h>
#include <math.h>

typedef _Float16 f16;
typedef f16 f16x2 __attribute__((ext_vector_type(2)));
typedef f16 f16x4 __attribute__((ext_vector_type(4)));
typedef f16 f16x8 __attribute__((ext_vector_type(8)));
typedef float f32x4_t __attribute__((ext_vector_type(4)));

__device__ __forceinline__ float sigmoidf(float x) {
  return 1.0f / (1.0f + __expf(-x));
}

// ---------------------------------------------------------------------------
// CSR build (by dst)
// ---------------------------------------------------------------------------
__global__ void zero_ints(int* __restrict__ p, int n) {
  int i = blockIdx.x * blockDim.x + threadIdx.x;
  if (i < n) p[i] = 0;
}

__global__ void count_kernel(const int* __restrict__ dst, int* __restrict__ cnt, int E) {
  int e = blockIdx.x * blockDim.x + threadIdx.x;
  if (e < E) atomicAdd(&cnt[dst[e]], 1);
}

__global__ void scan_kernel(const int* __restrict__ cnt, int* __restrict__ off,
                            int* __restrict__ cur, int n) {
  __shared__ int wsum[16];
  __shared__ int carry_s;
  const int tid = threadIdx.x;            // 1024 threads
  const int lane = tid & 63, wid = tid >> 6;
  if (tid == 0) carry_s = 0;
  __syncthreads();
  for (int base = 0; base < n; base += 1024) {
    int i = base + tid;
    int v = (i < n) ? cnt[i] : 0;
    int x = v;
    #pragma unroll
    for (int d = 1; d < 64; d <<= 1) {
      int y = __shfl_up(x, d);
      if (lane >= d) x += y;
    }
    if (lane == 63) wsum[wid] = x;
    __syncthreads();
    if (wid == 0) {
      int ws = (lane < 16) ? wsum[lane] : 0;
      #pragma unroll
      for (int d = 1; d < 16; d <<= 1) {
        int y = __shfl_up(ws, d);
        if (lane >= d) ws += y;
      }
      if (lane < 16) wsum[lane] = ws;
    }
    __syncthreads();
    int carry = carry_s;
    int woff = (wid > 0) ? wsum[wid - 1] : 0;
    int incl = x + woff;
    int excl = carry + incl - v;
    if (i < n) { off[i] = excl; cur[i] = excl; }
    __syncthreads();
    if (tid == 1023) carry_s = carry + incl;
    __syncthreads();
  }
  if (threadIdx.x == 0) { off[n] = carry_s; cur[n] = carry_s; }
}

__global__ void fill_kernel(const int* __restrict__ src, const int* __restrict__ dst,
                            int* __restrict__ cur, int* __restrict__ esrc, int E) {
  int e = blockIdx.x * blockDim.x + threadIdx.x;
  if (e < E) {
    int d = dst[e];
    int p = atomicAdd(&cur[d], 1);
    esrc[p] = src[e];
  }
}

// ---------------------------------------------------------------------------
// Weight pre-transpose: Wt[n][k] f16 from W[k][n] f32 (128 cols each source).
// blockIdx.z: 0=Wm(K=128)->WtM  1=Wz->WtZR[0:128)  2=Wr->WtZR[128:256)  3=Wh->WtH
// ---------------------------------------------------------------------------
__global__ void wtrans_all(const float* __restrict__ Wm, const float* __restrict__ Wz,
                           const float* __restrict__ Wr, const float* __restrict__ Wh,
                           f16* __restrict__ WtM, f16* __restrict__ WtZR,
                           f16* __restrict__ WtH) {
  __shared__ float tile[32][33];
  const float* W;
  f16* O;
  int K;
  switch (blockIdx.z) {
    case 0: W = Wm; O = WtM; K = 128; break;
    case 1: W = Wz; O = WtZR; K = 256; break;
    case 2: W = Wr; O = WtZR + 128 * 256; K = 256; break;
    default: W = Wh; O = WtH; K = 256; break;
  }
  int bk = blockIdx.x * 32, bn = blockIdx.y * 32;
  if (bk >= K) return;
  int tx = threadIdx.x, ty = threadIdx.y;   // 32 x 8
  #pragma unroll
  for (int i = 0; i < 4; ++i)
    tile[ty + 8 * i][tx] = W[(size_t)(bk + ty + 8 * i) * 128 + bn + tx];
  __syncthreads();
  #pragma unroll
  for (int i = 0; i < 4; ++i)
    O[(size_t)(bn + ty + 8 * i) * K + bk + tx] = (f16)tile[tx][ty + 8 * i];
}

// ---------------------------------------------------------------------------
// MFMA GEMM: C_f16[row][coff+c] = sum_terms A_t @ W_t   (K=128 per term)
// Wt: [NCOL][KTOT] f16 (k contiguous).  Block: 256 thr = 4 waves, tile 128x128.
// Wave: 64x64 = 4x4 fragments of 16x16, v_mfma_f32_16x16x32_f16, f32 acc.
// ---------------------------------------------------------------------------
template <int TERMS, int A0F32, int A1F32>
__global__ __launch_bounds__(256) void gemm_mfma(
    const void* __restrict__ A0v, const void* __restrict__ A1v,
    const f16* __restrict__ Wt, f16* __restrict__ C, int ldc, int N) {
  constexpr int KTOT = TERMS * 128;
  __shared__ __align__(16) f16 As[128][72];   // pad 72: <=2-way bank alias
  __shared__ __align__(16) f16 Bs[128][72];
  const int tid = threadIdx.x;
  const int l = tid & 63, w = tid >> 6;
  const int wr = (w >> 1) * 64, wc = (w & 1) * 64;
  const int fr = l & 15;            // row-in-frag (A) / col-in-frag (B)
  const int kg = (l >> 4) * 8;      // k offset within 32-step
  const int brow = blockIdx.x * 128;
  const int coff = blockIdx.y * 128;

  f32x4_t acc[4][4];
  #pragma unroll
  for (int m = 0; m < 4; ++m)
    #pragma unroll
    for (int n = 0; n < 4; ++n) acc[m][n] = (f32x4_t)0.0f;

  #pragma unroll
  for (int kk = 0; kk < KTOT; kk += 64) {
    const bool sel1 = (TERMS == 2) && (kk >= 128);
    const void* Av = sel1 ? A1v : A0v;
    const bool srcF32 = sel1 ? (A1F32 != 0) : (A0F32 != 0);
    const int klocal = sel1 ? (kk - 128) : kk;

    __syncthreads();
    // stage A: 128 rows x 64 k  (1024 granules of 8 f16)
    #pragma unroll
    for (int p = 0; p < 4; ++p) {
      int g = tid + 256 * p;
      int row = g >> 3;
      int kc = (g & 7) * 8;
      int grow = brow + row;
      f16x8 v = {};
      if (grow < N) {
        if (srcF32) {
          const float* Ap = (const float*)Av + (size_t)grow * 128 + klocal + kc;
          float4 u0 = *(const float4*)Ap;
          float4 u1 = *(const float4*)(Ap + 4);
          v[0] = (f16)u0.x; v[1] = (f16)u0.y; v[2] = (f16)u0.z; v[3] = (f16)u0.w;
          v[4] = (f16)u1.x; v[5] = (f16)u1.y; v[6] = (f16)u1.z; v[7] = (f16)u1.w;
        } else {
          v = *(const f16x8*)((const f16*)Av + (size_t)grow * 128 + klocal + kc);
        }
      }
      *(f16x8*)&As[row][kc] = v;
    }
    // stage B: 128 cols x 64 k from Wt (already transposed, f16)
    #pragma unroll
    for (int p = 0; p < 4; ++p) {
      int g = tid + 256 * p;
      int c = g >> 3;
      int kc = (g & 7) * 8;
      *(f16x8*)&Bs[c][kc] = *(const f16x8*)&Wt[(size_t)(coff + c) * KTOT + kk + kc];
    }
    __syncthreads();

    #pragma unroll
    for (int ks = 0; ks < 2; ++ks) {
      f16x8 a[4], b[4];
      #pragma unroll
      for (int m = 0; m < 4; ++m)
        a[m] = *(const f16x8*)&As[wr + m * 16 + fr][ks * 32 + kg];
      #pragma unroll
      for (int n = 0; n < 4; ++n)
        b[n] = *(const f16x8*)&Bs[wc + n * 16 + fr][ks * 32 + kg];
      #pragma unroll
      for (int m = 0; m < 4; ++m)
        #pragma unroll
        for (int n = 0; n < 4; ++n)
          acc[m][n] = __builtin_amdgcn_mfma_f32_16x16x32_f16(a[m], b[n], acc[m][n], 0, 0, 0);
    }
  }

  // C store: row = brow+wr+m*16+(l>>4)*4+r, col = coff+wc+n*16+fr
  const int rbase = (l >> 4) * 4;
  if (brow + 128 <= N) {
    #pragma unroll
    for (int m = 0; m < 4; ++m) {
      int row0 = brow + wr + m * 16 + rbase;
      #pragma unroll
      for (int n = 0; n < 4; ++n) {
        int col = coff + wc + n * 16 + fr;
        #pragma unroll
        for (int r = 0; r < 4; ++r)
          C[(size_t)(row0 + r) * ldc + col] = (f16)acc[m][n][r];
      }
    }
  } else {
    #pragma unroll
    for (int m = 0; m < 4; ++m) {
      int row0 = brow + wr + m * 16 + rbase;
      #pragma unroll
      for (int n = 0; n < 4; ++n) {
        int col = coff + wc + n * 16 + fr;
        #pragma unroll
        for (int r = 0; r < 4; ++r)
          if (row0 + r < N) C[(size_t)(row0 + r) * ldc + col] = (f16)acc[m][n][r];
      }
    }
  }
}

// ---------------------------------------------------------------------------
// Gathers: one wave per node, 4x edge unroll. All gathered tensors f16.
// ---------------------------------------------------------------------------
__global__ void gather_relu(const f16* __restrict__ T, const int* __restrict__ off,
                            const int* __restrict__ esrc, const float* __restrict__ bias,
                            f16* __restrict__ X, int N) {
  int w = (blockIdx.x * blockDim.x + threadIdx.x) >> 6;
  int lane = threadIdx.x & 63;
  if (w >= N) return;
  int beg = off[w], end = off[w + 1];
  float ax = 0.f, ay = 0.f;
  int j = beg;
  for (; j + 4 <= end; j += 4) {
    int r0 = esrc[j], r1 = esrc[j + 1], r2 = esrc[j + 2], r3 = esrc[j + 3];
    f16x2 v0 = *(const f16x2*)&T[(size_t)r0 * 128 + lane * 2];
    f16x2 v1 = *(const f16x2*)&T[(size_t)r1 * 128 + lane * 2];
    f16x2 v2 = *(const f16x2*)&T[(size_t)r2 * 128 + lane * 2];
    f16x2 v3 = *(const f16x2*)&T[(size_t)r3 * 128 + lane * 2];
    ax += ((float)v0.x + (float)v1.x) + ((float)v2.x + (float)v3.x);
    ay += ((float)v0.y + (float)v1.y) + ((float)v2.y + (float)v3.y);
  }
  for (; j < end; ++j) {
    f16x2 v = *(const f16x2*)&T[(size_t)esrc[j] * 128 + lane * 2];
    ax += (float)v.x; ay += (float)v.y;
  }
  float2 b = *(const float2*)&bias[lane * 2];
  f16x2 o;
  o.x = (f16)fmaxf(ax + b.x, 0.f);
  o.y = (f16)fmaxf(ay + b.y, 0.f);
  *(f16x2*)&X[(size_t)w * 128 + lane * 2] = o;
}

// P: [N][256] f16 = [z cols | r cols]. Lane covers 4 cols (8B).
// Lanes 0-31 -> Z (f16), lanes 32-63 -> G = sigmoid(r)*H (f16).
__global__ void gather_zr(const f16* __restrict__ P, const int* __restrict__ off,
                          const int* __restrict__ esrc, const float* __restrict__ bz,
                          const float* __restrict__ br, const float* __restrict__ H,
                          f16* __restrict__ Z, f16* __restrict__ G, int N) {
  int w = (blockIdx.x * blockDim.x + threadIdx.x) >> 6;
  int lane = threadIdx.x & 63;
  if (w >= N) return;
  int beg = off[w], end = off[w + 1];
  float a0 = 0.f, a1 = 0.f, a2 = 0.f, a3 = 0.f;
  int j = beg;
  for (; j + 4 <= end; j += 4) {
    int r0 = esrc[j], r1 = esrc[j + 1], r2 = esrc[j + 2], r3 = esrc[j + 3];
    f16x4 v0 = *(const f16x4*)&P[(size_t)r0 * 256 + lane * 4];
    f16x4 v1 = *(const f16x4*)&P[(size_t)r1 * 256 + lane * 4];
    f16x4 v2 = *(const f16x4*)&P[(size_t)r2 * 256 + lane * 4];
    f16x4 v3 = *(const f16x4*)&P[(size_t)r3 * 256 + lane * 4];
    a0 += ((float)v0.x + (float)v1.x) + ((float)v2.x + (float)v3.x);
    a1 += ((float)v0.y + (float)v1.y) + ((float)v2.y + (float)v3.y);
    a2 += ((float)v0.z + (float)v1.z) + ((float)v2.z + (float)v3.z);
    a3 += ((float)v0.w + (float)v1.w) + ((float)v2.w + (float)v3.w);
  }
  for (; j < end; ++j) {
    f16x4 v = *(const f16x4*)&P[(size_t)esrc[j] * 256 + lane * 4];
    a0 += (float)v.x; a1 += (float)v.y; a2 += (float)v.z; a3 += (float)v.w;
  }
  if (lane < 32) {
    int c = lane * 4;
    float4 b = *(const float4*)&bz[c];
    f16x4 o;
    o.x = (f16)sigmoidf(a0 + b.x);
    o.y = (f16)sigmoidf(a1 + b.y);
    o.z = (f16)sigmoidf(a2 + b.z);
    o.w = (f16)sigmoidf(a3 + b.w);
    *(f16x4*)&Z[(size_t)w * 128 + c] = o;
  } else {
    int c = (lane - 32) * 4;
    float4 b = *(const float4*)&br[c];
    float4 h = *(const float4*)&H[(size_t)w * 128 + c];
    f16x4 o;
    o.x = (f16)(sigmoidf(a0 + b.x) * h.x);
    o.y = (f16)(sigmoidf(a1 + b.y) * h.y);
    o.z = (f16)(sigmoidf(a2 + b.z) * h.z);
    o.w = (f16)(sigmoidf(a3 + b.w) * h.w);
    *(f16x4*)&G[(size_t)w * 128 + c] = o;
  }
}

__global__ void gather_out(const f16* __restrict__ T, const int* __restrict__ off,
                           const int* __restrict__ esrc, const float* __restrict__ bh,
                           const f16* __restrict__ Z, const float* __restrict__ H,
                           float* __restrict__ out, int N) {
  int w = (blockIdx.x * blockDim.x + threadIdx.x) >> 6;
  int lane = threadIdx.x & 63;
  if (w >= N) return;
  int beg = off[w], end = off[w + 1];
  float ax = 0.f, ay = 0.f;
  int j = beg;
  for (; j + 4 <= end; j += 4) {
    int r0 = esrc[j], r1 = esrc[j + 1], r2 = esrc[j + 2], r3 = esrc[j + 3];
    f16x2 v0 = *(const f16x2*)&T[(size_t)r0 * 128 + lane * 2];
    f16x2 v1 = *(const f16x2*)&T[(size_t)r1 * 128 + lane * 2];
    f16x2 v2 = *(const f16x2*)&T[(size_t)r2 * 128 + lane * 2];
    f16x2 v3 = *(const f16x2*)&T[(size_t)r3 * 128 + lane * 2];
    ax += ((float)v0.x + (float)v1.x) + ((float)v2.x + (float)v3.x);
    ay += ((float)v0.y + (float)v1.y) + ((float)v2.y + (float)v3.y);
  }
  for (; j < end; ++j) {
    f16x2 v = *(const f16x2*)&T[(size_t)esrc[j] * 128 + lane * 2];
    ax += (float)v.x; ay += (float)v.y;
  }
  float2 b = *(const float2*)&bh[lane * 2];
  float h0 = tanhf(ax + b.x), h1 = tanhf(ay + b.y);
  size_t q = (size_t)w * 128 + lane * 2;
  f16x2 zv = *(const f16x2*)&Z[q];
  float2 h = *(const float2*)&H[q];
  float z0 = (float)zv.x, z1 = (float)zv.y;
  float2 o;
  o.x = z0 * h.x + (1.0f - z0) * h0;
  o.y = z1 * h.y + (1.0f - z1) * h1;
  *(float2*)&out[q] = o;
}

// ---------------------------------------------------------------------------

extern "C" void kernel_launch(void* const* d_in, const int* in_sizes, int n_in,
                              void* d_out, int out_size, void* d_ws, size_t ws_size,
                              hipStream_t stream) {
  const float* nf = (const float*)d_in[0];
  const float* H  = (const float*)d_in[1];
  const int*   ei = (const int*)d_in[2];
  const float* Wm = (const float*)d_in[3];
  const float* bm = (const float*)d_in[4];
  const float* Wz = (const float*)d_in[5];
  const float* bz = (const float*)d_in[6];
  const float* Wr = (const float*)d_in[7];
  const float* br = (const float*)d_in[8];
  const float* Wh = (const float*)d_in[9];
  const float* bh = (const float*)d_in[10];
  float* out = (float*)d_out;

  const int N = in_sizes[0] / 128;
  const int E = in_sizes[2] / 2;
  const int* src = ei;       // edge_index[0]
  const int* dst = ei + E;   // edge_index[1]

  char* ws = (char*)d_ws;
  size_t o = 0;
  auto alloc = [&](size_t bytes) {
    char* p = ws + o;
    o = (o + bytes + 511) & ~(size_t)511;
    return p;
  };
  int* cnt    = (int*)alloc((size_t)N * 4);
  int* off    = (int*)alloc((size_t)(N + 1) * 4);
  int* cur    = (int*)alloc((size_t)(N + 1) * 4);
  int* esrc   = (int*)alloc((size_t)E * 4);
  f16* WtM    = (f16*)alloc((size_t)128 * 128 * 2);
  f16* WtZR   = (f16*)alloc((size_t)256 * 256 * 2);
  f16* WtH    = (f16*)alloc((size_t)128 * 256 * 2);
  f16* Tm     = (f16*)alloc((size_t)N * 128 * 2);
  f16* Pzr    = (f16*)alloc((size_t)N * 256 * 2);
  f16* Th     = (f16*)alloc((size_t)N * 128 * 2);
  f16* X      = (f16*)alloc((size_t)N * 128 * 2);
  f16* G      = (f16*)alloc((size_t)N * 128 * 2);
  f16* Zh     = (f16*)alloc((size_t)N * 128 * 2);

  // --- CSR build ---
  zero_ints<<<(N + 255) / 256, 256, 0, stream>>>(cnt, N);
  count_kernel<<<(E + 255) / 256, 256, 0, stream>>>(dst, cnt, E);
  scan_kernel<<<1, 1024, 0, stream>>>(cnt, off, cur, N);
  fill_kernel<<<(E + 255) / 256, 256, 0, stream>>>(src, dst, cur, esrc, E);

  // --- weight pre-transpose (f32 -> f16, [n][k]) ---
  wtrans_all<<<dim3(8, 4, 4), dim3(32, 8), 0, stream>>>(Wm, Wz, Wr, Wh, WtM, WtZR, WtH);

  const int gblk = (N * 64 + 255) / 256;   // one wave per node
  const int mblk = (N + 127) / 128;

  // --- main conv: X = relu(Agg(nf@Wm) + bm) ---
  gemm_mfma<1, 1, 0><<<dim3(mblk, 1), 256, 0, stream>>>(nf, nullptr, WtM, Tm, 128, N);
  gather_relu<<<gblk, 256, 0, stream>>>(Tm, off, esrc, bm, X, N);

  // --- fused Z|R conv: Pzr = [X,H] @ [[Wz0|Wr0],[Wz1|Wr1]] ---
  gemm_mfma<2, 0, 1><<<dim3(mblk, 2), 256, 0, stream>>>(X, H, WtZR, Pzr, 256, N);
  gather_zr<<<gblk, 256, 0, stream>>>(Pzr, off, esrc, bz, br, H, Zh, G, N);

  // --- H_tilde conv + output ---
  gemm_mfma<2, 0, 0><<<dim3(mblk, 1), 256, 0, stream>>>(X, G, WtH, Th, 128, N);
  gather_out<<<gblk, 256, 0, stream>>>(Th, off, esrc, bh, Zh, H, out, N);
}

// Round 4
// 329.870 us; speedup vs baseline: 2.0181x; 1.0137x over previous
//
#include <hip/hip_runtime.h>
#include <hip/hip_fp16.h>
#include <math.h>

typedef _Float16 f16;
typedef f16 f16x2 __attribute__((ext_vector_type(2)));
typedef f16 f16x4 __attribute__((ext_vector_type(4)));
typedef f16 f16x8 __attribute__((ext_vector_type(8)));
typedef float f32x4_t __attribute__((ext_vector_type(4)));

__device__ __forceinline__ float sigmoidf(float x) {
  return 1.0f / (1.0f + __expf(-x));
}

// ---------------------------------------------------------------------------
// CSR build (by dst).  eoff stores PRE-SCALED byte offsets: src*256
// (= row bytes of a 128-col f16 tensor; 256-col gather shifts left by 1).
// ---------------------------------------------------------------------------
__global__ void zero_ints(int* __restrict__ p, int n) {
  int i = blockIdx.x * blockDim.x + threadIdx.x;
  if (i < n) p[i] = 0;
}

__global__ void count_kernel(const int* __restrict__ dst, int* __restrict__ cnt, int E) {
  int e = blockIdx.x * blockDim.x + threadIdx.x;
  if (e < E) atomicAdd(&cnt[dst[e]], 1);
}

// 3-phase scan: local scan per 1024-chunk -> psum; scan psum; add carries.
__global__ __launch_bounds__(1024) void scan_local(const int* __restrict__ cnt,
                                                   int* __restrict__ off,
                                                   int* __restrict__ psum, int n) {
  __shared__ int wsum[16];
  const int tid = threadIdx.x, lane = tid & 63, wid = tid >> 6;
  int i = blockIdx.x * 1024 + tid;
  int v = (i < n) ? cnt[i] : 0;
  int x = v;
  #pragma unroll
  for (int d = 1; d < 64; d <<= 1) { int y = __shfl_up(x, d); if (lane >= d) x += y; }
  if (lane == 63) wsum[wid] = x;
  __syncthreads();
  if (wid == 0) {
    int ws = (lane < 16) ? wsum[lane] : 0;
    #pragma unroll
    for (int d = 1; d < 16; d <<= 1) { int y = __shfl_up(ws, d); if (lane >= d) ws += y; }
    if (lane < 16) wsum[lane] = ws;
  }
  __syncthreads();
  int excl = x - v + (wid ? wsum[wid - 1] : 0);
  if (i < n) off[i] = excl;
  if (tid == 1023) psum[blockIdx.x] = wsum[15];
}

__global__ __launch_bounds__(1024) void scan_carry(int* __restrict__ psum,
                                                   int* __restrict__ off,
                                                   int* __restrict__ cur, int nb, int n) {
  __shared__ int wsum[16];
  const int tid = threadIdx.x, lane = tid & 63, wid = tid >> 6;
  int v = (tid < nb) ? psum[tid] : 0;
  int x = v;
  #pragma unroll
  for (int d = 1; d < 64; d <<= 1) { int y = __shfl_up(x, d); if (lane >= d) x += y; }
  if (lane == 63) wsum[wid] = x;
  __syncthreads();
  if (wid == 0) {
    int ws = (lane < 16) ? wsum[lane] : 0;
    #pragma unroll
    for (int d = 1; d < 16; d <<= 1) { int y = __shfl_up(ws, d); if (lane >= d) ws += y; }
    if (lane < 16) wsum[lane] = ws;
  }
  __syncthreads();
  int excl = x - v + (wid ? wsum[wid - 1] : 0);
  if (tid < nb) psum[tid] = excl;
  if (tid == 1023) { off[n] = wsum[15]; cur[n] = wsum[15]; }
}

__global__ __launch_bounds__(1024) void scan_add(int* __restrict__ off, int* __restrict__ cur,
                                                 const int* __restrict__ psum, int n) {
  int i = blockIdx.x * 1024 + threadIdx.x;
  if (i < n) {
    int t = off[i] + psum[blockIdx.x];
    off[i] = t;
    cur[i] = t;
  }
}

__global__ void fill_kernel(const int* __restrict__ src, const int* __restrict__ dst,
                            int* __restrict__ cur, int* __restrict__ eoff, int E) {
  int e = blockIdx.x * blockDim.x + threadIdx.x;
  if (e < E) {
    int d = dst[e];
    int p = atomicAdd(&cur[d], 1);
    eoff[p] = src[e] << 8;   // src * 256 bytes
  }
}

// ---------------------------------------------------------------------------
// Pack P0[n] = [nf[n] | H[n]] as f16 [N,256]. One wave per node.
// ---------------------------------------------------------------------------
__global__ void pack_nfh(const float* __restrict__ nf, const float* __restrict__ H,
                         f16* __restrict__ P0, int N) {
  int gid = blockIdx.x * blockDim.x + threadIdx.x;
  int w = gid >> 6;
  if (w >= N) return;
  int lane = threadIdx.x & 63;
  const float* S = (lane < 32) ? nf : H;
  int c = (lane & 31) * 4;
  float4 u = *(const float4*)&S[(size_t)w * 128 + c];
  f16x4 o = {(f16)u.x, (f16)u.y, (f16)u.z, (f16)u.w};
  *(f16x4*)&P0[(size_t)w * 256 + (lane < 32 ? 0 : 128) + c] = o;
}

// ---------------------------------------------------------------------------
// Weight pre-transpose: Wt[n][k] f16 from W[k][n] f32.
// blockIdx.z: 0=Wm(K=128)->WtM  1=Wz->WtZR[0:128)  2=Wr->WtZR[128:256)  3=Wh->WtH
// ---------------------------------------------------------------------------
__global__ void wtrans_all(const float* __restrict__ Wm, const float* __restrict__ Wz,
                           const float* __restrict__ Wr, const float* __restrict__ Wh,
                           f16* __restrict__ WtM, f16* __restrict__ WtZR,
                           f16* __restrict__ WtH) {
  __shared__ float tile[32][33];
  const float* W;
  f16* O;
  int K;
  switch (blockIdx.z) {
    case 0: W = Wm; O = WtM; K = 128; break;
    case 1: W = Wz; O = WtZR; K = 256; break;
    case 2: W = Wr; O = WtZR + 128 * 256; K = 256; break;
    default: W = Wh; O = WtH; K = 256; break;
  }
  int bk = blockIdx.x * 32, bn = blockIdx.y * 32;
  if (bk >= K) return;
  int tx = threadIdx.x, ty = threadIdx.y;   // 32 x 8
  #pragma unroll
  for (int i = 0; i < 4; ++i)
    tile[ty + 8 * i][tx] = W[(size_t)(bk + ty + 8 * i) * 128 + bn + tx];
  __syncthreads();
  #pragma unroll
  for (int i = 0; i < 4; ++i)
    O[(size_t)(bn + ty + 8 * i) * K + bk + tx] = (f16)tile[tx][ty + 8 * i];
}

// ---------------------------------------------------------------------------
// Gather: O[v] = sum over in-edges of P[src].  One wave per node, uniform
// (scalar) index loads, pre-scaled byte offsets, 8-deep MLP, f32 accumulate.
// COLS = 256 (8B/lane) or 128 (4B/lane).
// ---------------------------------------------------------------------------
template <int COLS>
__global__ __launch_bounds__(256) void gather(const f16* __restrict__ P,
                                              const int* __restrict__ off,
                                              const int* __restrict__ eoff,
                                              f16* __restrict__ O, int N) {
  int gid = blockIdx.x * blockDim.x + threadIdx.x;
  int w = __builtin_amdgcn_readfirstlane(gid >> 6);
  if (w >= N) return;
  const int lane = threadIdx.x & 63;
  const int beg = off[w], end = off[w + 1];
  const char* base = (const char*)P;
  int j = beg;
  if constexpr (COLS == 256) {
    const int lb = lane * 8;
    float a0 = 0.f, a1 = 0.f, a2 = 0.f, a3 = 0.f;
    for (; j + 8 <= end; j += 8) {
      f16x4 v[8];
      #pragma unroll
      for (int u = 0; u < 8; ++u) {
        int bo = (eoff[j + u] << 1) + lb;
        v[u] = *(const f16x4*)(base + bo);
      }
      #pragma unroll
      for (int u = 0; u < 8; ++u) {
        a0 += (float)v[u].x; a1 += (float)v[u].y;
        a2 += (float)v[u].z; a3 += (float)v[u].w;
      }
    }
    for (; j < end; ++j) {
      int bo = (eoff[j] << 1) + lb;
      f16x4 v = *(const f16x4*)(base + bo);
      a0 += (float)v.x; a1 += (float)v.y; a2 += (float)v.z; a3 += (float)v.w;
    }
    f16x4 o = {(f16)a0, (f16)a1, (f16)a2, (f16)a3};
    *(f16x4*)&O[(size_t)w * 256 + lane * 4] = o;
  } else {
    const int lb = lane * 4;
    float a0 = 0.f, a1 = 0.f;
    for (; j + 8 <= end; j += 8) {
      f16x2 v[8];
      #pragma unroll
      for (int u = 0; u < 8; ++u)
        v[u] = *(const f16x2*)(base + eoff[j + u] + lb);
      #pragma unroll
      for (int u = 0; u < 8; ++u) { a0 += (float)v[u].x; a1 += (float)v[u].y; }
    }
    for (; j < end; ++j) {
      f16x2 v = *(const f16x2*)(base + eoff[j] + lb);
      a0 += (float)v.x; a1 += (float)v.y;
    }
    f16x2 o = {(f16)a0, (f16)a1};
    *(f16x2*)&O[(size_t)w * 128 + lane * 2] = o;
  }
}

// ---------------------------------------------------------------------------
// MFMA GEMM with fused epilogues.  Tile 128x128, 4 waves, f16 in, f32 acc.
// A terms f16 with per-term lda.  B = Wt[n][k] (k contiguous), KTOT=TERMS*128.
// EPI 0: O0 = relu(acc + b0)                       (f16, ldo 128)
// EPI 1: blockIdx.y==0: O0 = sig(acc+b0)           (Z, f16)
//        blockIdx.y==1: O1 = sig(acc+b1)*H         (G, f16)
// EPI 2: Ofp = Zh*H + (1-Zh)*tanh(acc+b0)          (f32 final output)
// ---------------------------------------------------------------------------
template <int TERMS, int EPI>
__global__ __launch_bounds__(256) void gemm_mfma(
    const f16* __restrict__ A0, int lda0, const f16* __restrict__ A1, int lda1,
    const f16* __restrict__ Wt,
    const float* __restrict__ b0, const float* __restrict__ b1,
    const float* __restrict__ H, const f16* __restrict__ Zh,
    f16* __restrict__ O0, f16* __restrict__ O1, float* __restrict__ Ofp, int N) {
  constexpr int KTOT = TERMS * 128;
  __shared__ __align__(16) f16 As[128][72];
  __shared__ __align__(16) f16 Bs[128][72];
  const int tid = threadIdx.x;
  const int l = tid & 63, w = tid >> 6;
  const int wr = (w >> 1) * 64, wc = (w & 1) * 64;
  const int fr = l & 15;
  const int kg = (l >> 4) * 8;
  const int brow = blockIdx.x * 128;
  const int coff = blockIdx.y * 128;

  f32x4_t acc[4][4];
  #pragma unroll
  for (int m = 0; m < 4; ++m)
    #pragma unroll
    for (int n = 0; n < 4; ++n) acc[m][n] = (f32x4_t)0.0f;

  #pragma unroll
  for (int kk = 0; kk < KTOT; kk += 64) {
    const bool sel1 = (TERMS == 2) && (kk >= 128);
    const f16* __restrict__ A = sel1 ? A1 : A0;
    const int lda = sel1 ? lda1 : lda0;
    const int klocal = kk & 127;

    __syncthreads();
    #pragma unroll
    for (int p = 0; p < 4; ++p) {
      int g = tid + 256 * p;
      int row = g >> 3;
      int kc = (g & 7) * 8;
      int grow = brow + row;
      f16x8 v = {};
      if (grow < N) v = *(const f16x8*)&A[(size_t)grow * lda + klocal + kc];
      *(f16x8*)&As[row][kc] = v;
    }
    #pragma unroll
    for (int p = 0; p < 4; ++p) {
      int g = tid + 256 * p;
      int c = g >> 3;
      int kc = (g & 7) * 8;
      *(f16x8*)&Bs[c][kc] = *(const f16x8*)&Wt[(size_t)(coff + c) * KTOT + kk + kc];
    }
    __syncthreads();

    #pragma unroll
    for (int ks = 0; ks < 2; ++ks) {
      f16x8 a[4], b[4];
      #pragma unroll
      for (int m = 0; m < 4; ++m)
        a[m] = *(const f16x8*)&As[wr + m * 16 + fr][ks * 32 + kg];
      #pragma unroll
      for (int n = 0; n < 4; ++n)
        b[n] = *(const f16x8*)&Bs[wc + n * 16 + fr][ks * 32 + kg];
      #pragma unroll
      for (int m = 0; m < 4; ++m)
        #pragma unroll
        for (int n = 0; n < 4; ++n)
          acc[m][n] = __builtin_amdgcn_mfma_f32_16x16x32_f16(a[m], b[n], acc[m][n], 0, 0, 0);
    }
  }

  const int rbase = (l >> 4) * 4;
  #pragma unroll
  for (int m = 0; m < 4; ++m) {
    int row0 = brow + wr + m * 16 + rbase;
    #pragma unroll
    for (int n = 0; n < 4; ++n) {
      int colL = wc + n * 16 + fr;          // 0..127 within this col-block
      if (EPI == 0) {
        float bias = b0[colL];
        #pragma unroll
        for (int r = 0; r < 4; ++r) {
          int row = row0 + r;
          if (row < N)
            O0[(size_t)row * 128 + colL] = (f16)fmaxf(acc[m][n][r] + bias, 0.f);
        }
      } else if (EPI == 1) {
        if (coff == 0) {
          float bias = b0[colL];
          #pragma unroll
          for (int r = 0; r < 4; ++r) {
            int row = row0 + r;
            if (row < N)
              O0[(size_t)row * 128 + colL] = (f16)sigmoidf(acc[m][n][r] + bias);
          }
        } else {
          float bias = b1[colL];
          #pragma unroll
          for (int r = 0; r < 4; ++r) {
            int row = row0 + r;
            if (row < N) {
              float g = sigmoidf(acc[m][n][r] + bias) * H[(size_t)row * 128 + colL];
              O1[(size_t)row * 128 + colL] = (f16)g;
            }
          }
        }
      } else {
        float bias = b0[colL];
        #pragma unroll
        for (int r = 0; r < 4; ++r) {
          int row = row0 + r;
          if (row < N) {
            size_t q = (size_t)row * 128 + colL;
            float ht = tanhf(acc[m][n][r] + bias);
            float z = (float)Zh[q];
            float h = H[q];
            Ofp[q] = z * h + (1.0f - z) * ht;
          }
        }
      }
    }
  }
}

// ---------------------------------------------------------------------------

extern "C" void kernel_launch(void* const* d_in, const int* in_sizes, int n_in,
                              void* d_out, int out_size, void* d_ws, size_t ws_size,
                              hipStream_t stream) {
  const float* nf = (const float*)d_in[0];
  const float* H  = (const float*)d_in[1];
  const int*   ei = (const int*)d_in[2];
  const float* Wm = (const float*)d_in[3];
  const float* bm = (const float*)d_in[4];
  const float* Wz = (const float*)d_in[5];
  const float* bz = (const float*)d_in[6];
  const float* Wr = (const float*)d_in[7];
  const float* br = (const float*)d_in[8];
  const float* Wh = (const float*)d_in[9];
  const float* bh = (const float*)d_in[10];
  float* out = (float*)d_out;

  const int N = in_sizes[0] / 128;
  const int E = in_sizes[2] / 2;
  const int* src = ei;
  const int* dst = ei + E;

  char* ws = (char*)d_ws;
  size_t o = 0;
  auto alloc = [&](size_t bytes) {
    char* p = ws + o;
    o = (o + bytes + 511) & ~(size_t)511;
    return p;
  };
  const int nb = (N + 1023) / 1024;          // scan chunks
  int* cnt    = (int*)alloc((size_t)N * 4);
  int* off    = (int*)alloc((size_t)(N + 1) * 4);
  int* cur    = (int*)alloc((size_t)(N + 1) * 4);
  int* eoff   = (int*)alloc((size_t)E * 4);
  int* psum   = (int*)alloc((size_t)nb * 4);
  f16* WtM    = (f16*)alloc((size_t)128 * 128 * 2);
  f16* WtZR   = (f16*)alloc((size_t)256 * 256 * 2);
  f16* WtH    = (f16*)alloc((size_t)128 * 256 * 2);
  f16* P0     = (f16*)alloc((size_t)N * 256 * 2);   // [nf|H] packed
  f16* X      = (f16*)alloc((size_t)N * 128 * 2);
  f16* AX     = (f16*)alloc((size_t)N * 128 * 2);
  f16* G      = (f16*)alloc((size_t)N * 128 * 2);
  f16* AP0    = (f16*)d_out;                        // [Anf|AH]; dead before final write
  f16* Zh     = X;                                  // X dead after gather(X)
  f16* AG     = P0;                                 // P0 dead after gather(P0)

  // --- CSR build ---
  zero_ints<<<(N + 255) / 256, 256, 0, stream>>>(cnt, N);
  count_kernel<<<(E + 255) / 256, 256, 0, stream>>>(dst, cnt, E);
  scan_local<<<nb, 1024, 0, stream>>>(cnt, off, psum, N);
  scan_carry<<<1, 1024, 0, stream>>>(psum, off, cur, nb, N);
  scan_add<<<nb, 1024, 0, stream>>>(off, cur, psum, N);
  fill_kernel<<<(E + 255) / 256, 256, 0, stream>>>(src, dst, cur, eoff, E);

  // --- weight transpose + input pack ---
  wtrans_all<<<dim3(8, 4, 4), dim3(32, 8), 0, stream>>>(Wm, Wz, Wr, Wh, WtM, WtZR, WtH);
  const int gblk = (N * 64 + 255) / 256;
  pack_nfh<<<gblk, 256, 0, stream>>>(nf, H, P0, N);

  const int mblk = (N + 127) / 128;

  // --- aggregate [nf|H] once ---
  gather<256><<<gblk, 256, 0, stream>>>(P0, off, eoff, AP0, N);

  // --- X = relu(Anf @ Wm + bm) ---
  gemm_mfma<1, 0><<<dim3(mblk, 1), 256, 0, stream>>>(
      AP0, 256, nullptr, 0, WtM, bm, nullptr, nullptr, nullptr, X, nullptr, nullptr, N);

  // --- AX = Agg(X) ---
  gather<128><<<gblk, 256, 0, stream>>>(X, off, eoff, AX, N);

  // --- Z = sig([AX,AH]@Wz+bz), G = sig([AX,AH]@Wr+br)*H ---
  gemm_mfma<2, 1><<<dim3(mblk, 2), 256, 0, stream>>>(
      AX, 128, AP0 + 128, 256, WtZR, bz, br, H, nullptr, Zh, G, nullptr, N);

  // --- AG = Agg(G) ---
  gather<128><<<gblk, 256, 0, stream>>>(G, off, eoff, AG, N);

  // --- out = Zh*H + (1-Zh)*tanh([AX,AG]@Wh + bh) ---
  gemm_mfma<2, 2><<<dim3(mblk, 1), 256, 0, stream>>>(
      AX, 128, AG, 128, WtH, bh, nullptr, H, Zh, nullptr, nullptr, out, N);
}

// Round 5
// 304.016 us; speedup vs baseline: 2.1897x; 1.0850x over previous
//
#include <hip/hip_runtime.h>
#include <hip/hip_fp16.h>
#include <math.h>

typedef _Float16 f16;
typedef f16 f16x2 __attribute__((ext_vector_type(2)));
typedef f16 f16x4 __attribute__((ext_vector_type(4)));
typedef f16 f16x8 __attribute__((ext_vector_type(8)));
typedef float f32x4_t __attribute__((ext_vector_type(4)));

__device__ __forceinline__ float sigmoidf(float x) {
  return 1.0f / (1.0f + __expf(-x));
}

// direct-to-LDS 16B copy: LDS dest = wave-uniform base + lane*16
#define GLDS16(gp, lp)                                                     \
  __builtin_amdgcn_global_load_lds(                                        \
      (const __attribute__((address_space(1))) void*)(gp),                 \
      (__attribute__((address_space(3))) void*)(lp), 16, 0, 0)

// ---------------------------------------------------------------------------
// CSR build (by dst)
// ---------------------------------------------------------------------------
__global__ void zero_ints(int* __restrict__ p, int n) {
  int i = blockIdx.x * blockDim.x + threadIdx.x;
  if (i < n) p[i] = 0;
}

__global__ void count_kernel(const int* __restrict__ dst, int* __restrict__ cnt, int E) {
  int base = (blockIdx.x * blockDim.x + threadIdx.x) * 4;
  if (base + 3 < E) {
    int4 d = *(const int4*)&dst[base];
    atomicAdd(&cnt[d.x], 1);
    atomicAdd(&cnt[d.y], 1);
    atomicAdd(&cnt[d.z], 1);
    atomicAdd(&cnt[d.w], 1);
  } else {
    for (int e = base; e < E; ++e) atomicAdd(&cnt[dst[e]], 1);
  }
}

// 3-phase scan
__global__ __launch_bounds__(1024) void scan_local(const int* __restrict__ cnt,
                                                   int* __restrict__ off,
                                                   int* __restrict__ psum, int n) {
  __shared__ int wsum[16];
  const int tid = threadIdx.x, lane = tid & 63, wid = tid >> 6;
  int i = blockIdx.x * 1024 + tid;
  int v = (i < n) ? cnt[i] : 0;
  int x = v;
  #pragma unroll
  for (int d = 1; d < 64; d <<= 1) { int y = __shfl_up(x, d); if (lane >= d) x += y; }
  if (lane == 63) wsum[wid] = x;
  __syncthreads();
  if (wid == 0) {
    int ws = (lane < 16) ? wsum[lane] : 0;
    #pragma unroll
    for (int d = 1; d < 16; d <<= 1) { int y = __shfl_up(ws, d); if (lane >= d) ws += y; }
    if (lane < 16) wsum[lane] = ws;
  }
  __syncthreads();
  int excl = x - v + (wid ? wsum[wid - 1] : 0);
  if (i < n) off[i] = excl;
  if (tid == 1023) psum[blockIdx.x] = wsum[15];
}

__global__ __launch_bounds__(1024) void scan_carry(int* __restrict__ psum,
                                                   int* __restrict__ off,
                                                   int* __restrict__ cur, int nb, int n) {
  __shared__ int wsum[16];
  const int tid = threadIdx.x, lane = tid & 63, wid = tid >> 6;
  int v = (tid < nb) ? psum[tid] : 0;
  int x = v;
  #pragma unroll
  for (int d = 1; d < 64; d <<= 1) { int y = __shfl_up(x, d); if (lane >= d) x += y; }
  if (lane == 63) wsum[wid] = x;
  __syncthreads();
  if (wid == 0) {
    int ws = (lane < 16) ? wsum[lane] : 0;
    #pragma unroll
    for (int d = 1; d < 16; d <<= 1) { int y = __shfl_up(ws, d); if (lane >= d) ws += y; }
    if (lane < 16) wsum[lane] = ws;
  }
  __syncthreads();
  int excl = x - v + (wid ? wsum[wid - 1] : 0);
  if (tid < nb) psum[tid] = excl;
  if (tid == 1023) { off[n] = wsum[15]; cur[n] = wsum[15]; }
}

__global__ __launch_bounds__(1024) void scan_add(int* __restrict__ off, int* __restrict__ cur,
                                                 const int* __restrict__ psum, int n) {
  int i = blockIdx.x * 1024 + threadIdx.x;
  if (i < n) {
    int t = off[i] + psum[blockIdx.x];
    off[i] = t;
    cur[i] = t;
  }
}

// fill: 4 edges/thread -> 4 outstanding returning atomics; IDX = ushort or int
template <typename IDX>
__global__ void fill_kernel(const int* __restrict__ src, const int* __restrict__ dst,
                            int* __restrict__ cur, IDX* __restrict__ eidx, int E) {
  int base = (blockIdx.x * blockDim.x + threadIdx.x) * 4;
  if (base + 3 < E) {
    int4 d = *(const int4*)&dst[base];
    int4 s = *(const int4*)&src[base];
    int p0 = atomicAdd(&cur[d.x], 1);
    int p1 = atomicAdd(&cur[d.y], 1);
    int p2 = atomicAdd(&cur[d.z], 1);
    int p3 = atomicAdd(&cur[d.w], 1);
    eidx[p0] = (IDX)s.x;
    eidx[p1] = (IDX)s.y;
    eidx[p2] = (IDX)s.z;
    eidx[p3] = (IDX)s.w;
  } else {
    for (int e = base; e < E; ++e) {
      int p = atomicAdd(&cur[dst[e]], 1);
      eidx[p] = (IDX)src[e];
    }
  }
}

// ---------------------------------------------------------------------------
// Pack P0[n] = [nf[n] | H[n]] as f16 [N,256]
// ---------------------------------------------------------------------------
__global__ void pack_nfh(const float* __restrict__ nf, const float* __restrict__ H,
                         f16* __restrict__ P0, int N) {
  int gid = blockIdx.x * blockDim.x + threadIdx.x;
  int w = gid >> 6;
  if (w >= N) return;
  int lane = threadIdx.x & 63;
  const float* S = (lane < 32) ? nf : H;
  int c = (lane & 31) * 4;
  float4 u = *(const float4*)&S[(size_t)w * 128 + c];
  f16x4 o = {(f16)u.x, (f16)u.y, (f16)u.z, (f16)u.w};
  *(f16x4*)&P0[(size_t)w * 256 + (lane < 32 ? 0 : 128) + c] = o;
}

// ---------------------------------------------------------------------------
// Weight pre-transpose: Wt[n][k] f16 from W[k][n] f32
// ---------------------------------------------------------------------------
__global__ void wtrans_all(const float* __restrict__ Wm, const float* __restrict__ Wz,
                           const float* __restrict__ Wr, const float* __restrict__ Wh,
                           f16* __restrict__ WtM, f16* __restrict__ WtZR,
                           f16* __restrict__ WtH) {
  __shared__ float tile[32][33];
  const float* W;
  f16* O;
  int K;
  switch (blockIdx.z) {
    case 0: W = Wm; O = WtM; K = 128; break;
    case 1: W = Wz; O = WtZR; K = 256; break;
    case 2: W = Wr; O = WtZR + 128 * 256; K = 256; break;
    default: W = Wh; O = WtH; K = 256; break;
  }
  int bk = blockIdx.x * 32, bn = blockIdx.y * 32;
  if (bk >= K) return;
  int tx = threadIdx.x, ty = threadIdx.y;   // 32 x 8
  #pragma unroll
  for (int i = 0; i < 4; ++i)
    tile[ty + 8 * i][tx] = W[(size_t)(bk + ty + 8 * i) * 128 + bn + tx];
  __syncthreads();
  #pragma unroll
  for (int i = 0; i < 4; ++i)
    O[(size_t)(bn + ty + 8 * i) * K + bk + tx] = (f16)tile[tx][ty + 8 * i];
}

// ---------------------------------------------------------------------------
// Gather: one wave per node, scalar index loads, 8-deep MLP, f32 accumulate.
// ---------------------------------------------------------------------------
template <int COLS, typename IDX>
__global__ __launch_bounds__(256) void gather(const f16* __restrict__ P,
                                              const int* __restrict__ off,
                                              const IDX* __restrict__ eidx,
                                              f16* __restrict__ O, int N) {
  int gid = blockIdx.x * blockDim.x + threadIdx.x;
  int w = __builtin_amdgcn_readfirstlane(gid >> 6);
  if (w >= N) return;
  const int lane = threadIdx.x & 63;
  const int beg = off[w], end = off[w + 1];
  const char* base = (const char*)P;
  constexpr int SH = (COLS == 256) ? 9 : 8;   // row bytes = COLS*2
  int j = beg;
  if constexpr (COLS == 256) {
    const int lb = lane * 8;
    float a0 = 0.f, a1 = 0.f, a2 = 0.f, a3 = 0.f;
    for (; j + 8 <= end; j += 8) {
      f16x4 v[8];
      #pragma unroll
      for (int u = 0; u < 8; ++u)
        v[u] = *(const f16x4*)(base + (((int)eidx[j + u]) << SH) + lb);
      #pragma unroll
      for (int u = 0; u < 8; ++u) {
        a0 += (float)v[u].x; a1 += (float)v[u].y;
        a2 += (float)v[u].z; a3 += (float)v[u].w;
      }
    }
    for (; j < end; ++j) {
      f16x4 v = *(const f16x4*)(base + (((int)eidx[j]) << SH) + lb);
      a0 += (float)v.x; a1 += (float)v.y; a2 += (float)v.z; a3 += (float)v.w;
    }
    f16x4 o = {(f16)a0, (f16)a1, (f16)a2, (f16)a3};
    *(f16x4*)&O[(size_t)w * 256 + lane * 4] = o;
  } else {
    const int lb = lane * 4;
    float a0 = 0.f, a1 = 0.f;
    for (; j + 8 <= end; j += 8) {
      f16x2 v[8];
      #pragma unroll
      for (int u = 0; u < 8; ++u)
        v[u] = *(const f16x2*)(base + (((int)eidx[j + u]) << SH) + lb);
      #pragma unroll
      for (int u = 0; u < 8; ++u) { a0 += (float)v[u].x; a1 += (float)v[u].y; }
    }
    for (; j < end; ++j) {
      f16x2 v = *(const f16x2*)(base + (((int)eidx[j]) << SH) + lb);
      a0 += (float)v.x; a1 += (float)v.y;
    }
    f16x2 o = {(f16)a0, (f16)a1};
    *(f16x2*)&O[(size_t)w * 128 + lane * 2] = o;
  }
}

// ---------------------------------------------------------------------------
// MFMA GEMM v2.  Tile 64 rows x 128 cols, 4 waves (wave = 16 rows x 128 cols),
// BK=64, LDS XOR-granule-swizzled, global_load_lds staging with pre-swizzled
// per-lane SOURCE (linear LDS dest).  f16 in, f32 acc.
// EPI 0: O0 = relu(acc+b0)
// EPI 1: coff==0: O0 = sig(acc+b0);  coff!=0: O1 = sig(acc+b1)*H
// EPI 2: Ofp = Zh*H + (1-Zh)*tanh(acc+b0)
// ---------------------------------------------------------------------------
template <int TERMS, int EPI>
__global__ __launch_bounds__(256) void gemm_mfma(
    const f16* __restrict__ A0, int lda0, const f16* __restrict__ A1, int lda1,
    const f16* __restrict__ Wt,
    const float* __restrict__ b0, const float* __restrict__ b1,
    const float* __restrict__ H, const f16* __restrict__ Zh,
    f16* __restrict__ O0, f16* __restrict__ O1, float* __restrict__ Ofp, int N) {
  constexpr int KTOT = TERMS * 128;
  __shared__ __align__(16) f16 As[64][64];    // granule g at col (g^(row&7))*8
  __shared__ __align__(16) f16 Bs[128][64];
  f16* Asf = &As[0][0];
  f16* Bsf = &Bs[0][0];
  const int tid = threadIdx.x;
  const int l = tid & 63;
  const int wv = __builtin_amdgcn_readfirstlane(tid >> 6);
  const int fr = l & 15;
  const int q = l >> 4;             // 0..3
  const int brow = blockIdx.x * 64;
  const int coff = blockIdx.y * 128;
  const int rowA = wv * 16 + fr;    // tile-local A row this lane consumes
  const int sl8 = l >> 3, sg = l & 7;   // staging: sub-row, granule

  f32x4_t acc[8];
  #pragma unroll
  for (int n = 0; n < 8; ++n) acc[n] = (f32x4_t)0.0f;

  #pragma unroll
  for (int kk = 0; kk < KTOT; kk += 64) {
    const bool sel1 = (TERMS == 2) && (kk >= 128);
    const f16* __restrict__ A = sel1 ? A1 : A0;
    const int lda = sel1 ? lda1 : lda0;
    const int klocal = kk & 127;

    __syncthreads();   // previous step's LDS reads done
    // stage A: 64x64 f16 = 8 chunks of 1KB; wave wv -> chunks wv, wv+4
    #pragma unroll
    for (int c = 0; c < 2; ++c) {
      int chunk = wv + c * 4;
      int row = chunk * 8 + sl8;
      int gs = sg ^ (row & 7);                 // inverse-swizzled source granule
      int grow = brow + row;
      if (grow > N - 1) grow = N - 1;
      GLDS16(A + (size_t)grow * lda + klocal + gs * 8, Asf + chunk * 512);
    }
    // stage B: 128x64 f16 = 16 chunks; wave wv -> chunks wv+4c
    #pragma unroll
    for (int c = 0; c < 4; ++c) {
      int chunk = wv + c * 4;
      int col = chunk * 8 + sl8;
      int gs = sg ^ (col & 7);
      GLDS16(Wt + (size_t)(coff + col) * KTOT + kk + gs * 8, Bsf + chunk * 512);
    }
    asm volatile("s_waitcnt vmcnt(0)" ::: "memory");
    __syncthreads();

    #pragma unroll
    for (int ks = 0; ks < 2; ++ks) {
      f16x8 a = *(const f16x8*)&As[rowA][((ks * 4 + q) ^ (rowA & 7)) * 8];
      f16x8 b[8];
      #pragma unroll
      for (int n = 0; n < 8; ++n) {
        int colB = n * 16 + fr;
        b[n] = *(const f16x8*)&Bs[colB][((ks * 4 + q) ^ (colB & 7)) * 8];
      }
      #pragma unroll
      for (int n = 0; n < 8; ++n)
        acc[n] = __builtin_amdgcn_mfma_f32_16x16x32_f16(a, b[n], acc[n], 0, 0, 0);
    }
  }

  // C: row = brow + wv*16 + q*4 + r, col = coff + n*16 + fr
  const int row0 = brow + wv * 16 + q * 4;
  #pragma unroll
  for (int n = 0; n < 8; ++n) {
    int colL = n * 16 + fr;
    if (EPI == 0) {
      float bias = b0[colL];
      #pragma unroll
      for (int r = 0; r < 4; ++r) {
        int row = row0 + r;
        if (row < N)
          O0[(size_t)row * 128 + colL] = (f16)fmaxf(acc[n][r] + bias, 0.f);
      }
    } else if (EPI == 1) {
      if (coff == 0) {
        float bias = b0[colL];
        #pragma unroll
        for (int r = 0; r < 4; ++r) {
          int row = row0 + r;
          if (row < N)
            O0[(size_t)row * 128 + colL] = (f16)sigmoidf(acc[n][r] + bias);
        }
      } else {
        float bias = b1[colL];
        #pragma unroll
        for (int r = 0; r < 4; ++r) {
          int row = row0 + r;
          if (row < N) {
            float g = sigmoidf(acc[n][r] + bias) * H[(size_t)row * 128 + colL];
            O1[(size_t)row * 128 + colL] = (f16)g;
          }
        }
      }
    } else {
      float bias = b0[colL];
      #pragma unroll
      for (int r = 0; r < 4; ++r) {
        int row = row0 + r;
        if (row < N) {
          size_t p = (size_t)row * 128 + colL;
          float ht = tanhf(acc[n][r] + bias);
          float z = (float)Zh[p];
          float h = H[p];
          Ofp[p] = z * h + (1.0f - z) * ht;
        }
      }
    }
  }
}

// ---------------------------------------------------------------------------

extern "C" void kernel_launch(void* const* d_in, const int* in_sizes, int n_in,
                              void* d_out, int out_size, void* d_ws, size_t ws_size,
                              hipStream_t stream) {
  const float* nf = (const float*)d_in[0];
  const float* H  = (const float*)d_in[1];
  const int*   ei = (const int*)d_in[2];
  const float* Wm = (const float*)d_in[3];
  const float* bm = (const float*)d_in[4];
  const float* Wz = (const float*)d_in[5];
  const float* bz = (const float*)d_in[6];
  const float* Wr = (const float*)d_in[7];
  const float* br = (const float*)d_in[8];
  const float* Wh = (const float*)d_in[9];
  const float* bh = (const float*)d_in[10];
  float* out = (float*)d_out;

  const int N = in_sizes[0] / 128;
  const int E = in_sizes[2] / 2;
  const int* src = ei;
  const int* dst = ei + E;

  char* ws = (char*)d_ws;
  size_t o = 0;
  auto alloc = [&](size_t bytes) {
    char* p = ws + o;
    o = (o + bytes + 511) & ~(size_t)511;
    return p;
  };
  const int nb = (N + 1023) / 1024;
  int* cnt    = (int*)alloc((size_t)N * 4);
  int* off    = (int*)alloc((size_t)(N + 1) * 4);
  int* cur    = (int*)alloc((size_t)(N + 1) * 4);
  void* eidx  = (void*)alloc((size_t)E * 4);        // ushort or int
  int* psum   = (int*)alloc((size_t)nb * 4);
  f16* WtM    = (f16*)alloc((size_t)128 * 128 * 2);
  f16* WtZR   = (f16*)alloc((size_t)256 * 256 * 2);
  f16* WtH    = (f16*)alloc((size_t)128 * 256 * 2);
  f16* P0     = (f16*)alloc((size_t)N * 256 * 2);   // [nf|H] packed
  f16* X      = (f16*)alloc((size_t)N * 128 * 2);
  f16* AX     = (f16*)alloc((size_t)N * 128 * 2);
  f16* G      = (f16*)alloc((size_t)N * 128 * 2);
  f16* AP0    = (f16*)d_out;                        // dead before final write
  f16* Zh     = X;                                  // X dead after gather(X)
  f16* AG     = P0;                                 // P0 dead after gather(P0)

  const bool small = (N <= 65535);

  // --- CSR build ---
  zero_ints<<<(N + 255) / 256, 256, 0, stream>>>(cnt, N);
  const int qblk = ((E + 3) / 4 + 255) / 256;
  count_kernel<<<qblk, 256, 0, stream>>>(dst, cnt, E);
  scan_local<<<nb, 1024, 0, stream>>>(cnt, off, psum, N);
  scan_carry<<<1, 1024, 0, stream>>>(psum, off, cur, nb, N);
  scan_add<<<nb, 1024, 0, stream>>>(off, cur, psum, N);
  if (small)
    fill_kernel<unsigned short><<<qblk, 256, 0, stream>>>(src, dst, cur, (unsigned short*)eidx, E);
  else
    fill_kernel<int><<<qblk, 256, 0, stream>>>(src, dst, cur, (int*)eidx, E);

  // --- weight transpose + input pack ---
  wtrans_all<<<dim3(8, 4, 4), dim3(32, 8), 0, stream>>>(Wm, Wz, Wr, Wh, WtM, WtZR, WtH);
  const int gblk = (N * 64 + 255) / 256;
  pack_nfh<<<gblk, 256, 0, stream>>>(nf, H, P0, N);

  const int mblk = (N + 63) / 64;

  // --- AP0 = Agg([nf|H]) ---
  if (small)
    gather<256, unsigned short><<<gblk, 256, 0, stream>>>(P0, off, (const unsigned short*)eidx, AP0, N);
  else
    gather<256, int><<<gblk, 256, 0, stream>>>(P0, off, (const int*)eidx, AP0, N);

  // --- X = relu(Anf @ Wm + bm) ---
  gemm_mfma<1, 0><<<dim3(mblk, 1), 256, 0, stream>>>(
      AP0, 256, nullptr, 0, WtM, bm, nullptr, nullptr, nullptr, X, nullptr, nullptr, N);

  // --- AX = Agg(X) ---
  if (small)
    gather<128, unsigned short><<<gblk, 256, 0, stream>>>(X, off, (const unsigned short*)eidx, AX, N);
  else
    gather<128, int><<<gblk, 256, 0, stream>>>(X, off, (const int*)eidx, AX, N);

  // --- Z = sig([AX,AH]@Wz+bz), G = sig([AX,AH]@Wr+br)*H ---
  gemm_mfma<2, 1><<<dim3(mblk, 2), 256, 0, stream>>>(
      AX, 128, AP0 + 128, 256, WtZR, bz, br, H, nullptr, Zh, G, nullptr, N);

  // --- AG = Agg(G) ---
  if (small)
    gather<128, unsigned short><<<gblk, 256, 0, stream>>>(G, off, (const unsigned short*)eidx, AG, N);
  else
    gather<128, int><<<gblk, 256, 0, stream>>>(G, off, (const int*)eidx, AG, N);

  // --- out = Zh*H + (1-Zh)*tanh([AX,AG]@Wh + bh) ---
  gemm_mfma<2, 2><<<dim3(mblk, 1), 256, 0, stream>>>(
      AX, 128, AG, 128, WtH, bh, nullptr, H, Zh, nullptr, nullptr, out, N);
}